// Round 5
// baseline (573.722 us; speedup 1.0000x reference)
//
#include <hip/hip_runtime.h>
#include <hip/hip_bf16.h>

#define B_    16
#define CIN   64
#define Hn    64
#define Wn    64
#define HID   128
#define SXS2  72    // sX2 row stride in shorts (144B, 16B-aligned)
#define SHS   136   // sH  row stride in shorts (272B, 16B-aligned)
#define NJC   8     // j-chunks per batch (16 channels each)
#define NBLK  (B_ * NJC)
#define RETRY 6

typedef _Float16 h8_t __attribute__((ext_vector_type(8)));   // 8 fp16 (4 VGPRs)
typedef __attribute__((ext_vector_type(4))) float f4_t;

// d_ws layout:
//   [0, 512KB)        : LLC h-bufs [2][16][64][128] fp16-encoded (agent-scope copies, fallback)
//   [512KB, 1MB)      : L2  h-bufs (same layout; plain-store/sc0-load, same-XCD fast path)
//   [1MB, +4KB)       : per-b flag line (256B): flags[jc*4+wv] = rows completed by that wave
// Encoded value = sgn*(h+2), sgn = phase (h>>1)&1. Buffer parity = h&1. Max skew 1 row
// (validated handoff) => same (buffer,phase) aliases only at distance 4 rows: impossible.
#define HBUF_SHORTS (B_ * Wn * HID)
#define HBUF_BYTES  (HBUF_SHORTS * 2)
#define L2_OFF      (2 * HBUF_BYTES)
#define FLAGS_OFF   (4 * HBUF_BYTES)
#define FLG_STRIDE  256

static __device__ __forceinline__ float sigm(float z)  { return 1.f / (1.f + __expf(-z)); }
static __device__ __forceinline__ float tanhf_(float z){ return 2.f / (1.f + __expf(-2.f * z)) - 1.f; }

// lgkm-only barrier: never drains vmcnt (global loads/stores stay in flight).
#define BAR_LGKM() do { \
    asm volatile("s_waitcnt lgkmcnt(0)" ::: "memory"); \
    __builtin_amdgcn_s_barrier(); \
    __builtin_amdgcn_sched_barrier(0); \
} while (0)

// 8 qword loads through the local-XCD L2 (sc0 = L1 bypass, L2 serve) + full vm drain.
// The trailing vmcnt(0) also acks every outstanding store/prefetch of this wave, so this
// asm doubles as the producer-side drain when placed at the row tail. Outputs are
// early-clobber so they can't alias the address operands.
static __device__ __forceinline__ void poll8(const void* p0, const void* p1,
                                             const void* p2, const void* p3,
                                             unsigned long long q[8]) {
    asm volatile(
        "global_load_dwordx2 %0, %8, off sc0\n\t"
        "global_load_dwordx2 %1, %8, off offset:8 sc0\n\t"
        "global_load_dwordx2 %2, %9, off sc0\n\t"
        "global_load_dwordx2 %3, %9, off offset:8 sc0\n\t"
        "global_load_dwordx2 %4, %10, off sc0\n\t"
        "global_load_dwordx2 %5, %10, off offset:8 sc0\n\t"
        "global_load_dwordx2 %6, %11, off sc0\n\t"
        "global_load_dwordx2 %7, %11, off offset:8 sc0\n\t"
        "s_waitcnt vmcnt(0)"
        : "=&v"(q[0]), "=&v"(q[1]), "=&v"(q[2]), "=&v"(q[3]),
          "=&v"(q[4]), "=&v"(q[5]), "=&v"(q[6]), "=&v"(q[7])
        : "v"((unsigned long long)p0), "v"((unsigned long long)p1),
          "v"((unsigned long long)p2), "v"((unsigned long long)p3)
        : "memory");
}

// phase-validate one 8B word (check BOTH dwords: guards against dword tearing)
static __device__ __forceinline__ bool qvalid(unsigned long long q, unsigned short psign) {
    const unsigned short e0 = (unsigned short)q        ^ psign;
    const unsigned short e4 = (unsigned short)(q >> 32) ^ psign;
    return (e0 >= 0x3C00u) & (e0 <= 0x4200u) & (e4 >= 0x3C00u) & (e4 <= 0x4200u);
}

extern "C" __global__ __launch_bounds__(256, 1)
void rowlstm_kernel(const float* __restrict__ x,
                    const float* __restrict__ w_is,
                    const float* __restrict__ b_is,
                    const float* __restrict__ w_ss,
                    const float* __restrict__ b_ss,
                    float* __restrict__ out,
                    unsigned char* __restrict__ ws)
{
    const int tid  = threadIdx.x;
    const int bid  = blockIdx.x;
    const int b    = bid & 15;        // batch; same-b blocks share bid%8 -> same XCD (fast-path heuristic)
    const int jc   = bid >> 4;        // j-chunk: channels [jc*16, jc*16+16)
    const int lane = tid & 63;
    const int wv   = tid >> 6;        // wave id = N-tile (16 w's)
    const int l15  = lane & 15;
    const int quad = lane >> 4;

    short*    llc0  = (short*)ws;                       // LLC-coherent encoded h
    short*    l2b0  = (short*)(ws + L2_OFF);            // local-L2 encoded h
    unsigned* flags = (unsigned*)(ws + FLAGS_OFF + b * FLG_STRIDE);   // 32 words

    // LDS ~27 KB. Shifted-read panels: tap t of column w' reads row w'+t.
    __shared__ alignas(16) short sH[66 * SHS];    // h panel (ENCODED fp16), rows 0..65 (0,65 = guards)
    __shared__ alignas(16) short sX2[65 * SXS2];  // x panel fp16, rows 0..64 (0 = zero guard)
    __shared__ float sS3[4][16];                  // per (gate, ch-local) sum of fp16 h-weights

    // ---- A (weight) fragments, fp16, gate-major: M-row = mt*16 + l15 -> gate mt, ch l15.
    // K layout (512): [0,64) x kw0 | [64,128) x kw1 | [128,256) h kw0 | [256,384) h kw1 | [384,512) h kw2
    h8_t a_frag[4][16];
    #pragma unroll
    for (int mt = 0; mt < 4; ++mt) {
        const int co = mt * HID + jc * 16 + l15;
        #pragma unroll
        for (int kt = 0; kt < 16; ++kt) {
            const int kk0 = kt * 32 + quad * 8;
            const float* p;
            if      (kt < 2)  p = &w_is[(co * CIN + kk0)         * 3 + 0];
            else if (kt < 4)  p = &w_is[(co * CIN + (kk0 - 64))  * 3 + 1];
            else if (kt < 8)  p = &w_ss[(co * HID + (kk0 - 128)) * 3 + 0];
            else if (kt < 12) p = &w_ss[(co * HID + (kk0 - 256)) * 3 + 1];
            else              p = &w_ss[(co * HID + (kk0 - 384)) * 3 + 2];
            h8_t v;
            #pragma unroll
            for (int j = 0; j < 8; ++j) v[j] = (_Float16)p[j * 3];
            a_frag[mt][kt] = v;
        }
    }

    // ---- S3[g][ch] = sum of this channel's fp16 h-weights (kt 4..15): +2-offset correction.
    #pragma unroll
    for (int mt = 0; mt < 4; ++mt) {
        float s = 0.f;
        #pragma unroll
        for (int kt = 4; kt < 16; ++kt) {
            #pragma unroll
            for (int j = 0; j < 8; ++j) s += (float)a_frag[mt][kt][j];
        }
        s += __shfl_xor(s, 16);
        s += __shfl_xor(s, 32);
        if (wv == 0 && quad == 0) sS3[mt][l15] = s;
    }

    // zero guard row for x panel (true zero, never touched again)
    {
        h8_t z8 = {0,0,0,0,0,0,0,0};
        if (tid < 8) *(h8_t*)&sX2[tid * 8] = z8;
    }
    __syncthreads();

    // combined bias: b_is + b_ss - 2*S3 (cancels the +2 encoding offset, guards included)
    float bias2[4][4];
    #pragma unroll
    for (int g = 0; g < 4; ++g) {
        #pragma unroll
        for (int r = 0; r < 4; ++r) {
            const int co = g * HID + jc * 16 + quad * 4 + r;
            bias2[g][r] = b_is[co] + b_ss[co] - 2.f * sS3[g][quad * 4 + r];
        }
    }

    float creg[4] = {0.f, 0.f, 0.f, 0.f};
    const int wp  = wv * 16 + l15;

    const int xw  = tid & 63;
    const int xc2 = tid >> 6;
    float xr[16];
    #pragma unroll
    for (int e = 0; e < 16; ++e)
        xr[e] = x[((b * CIN + xc2 * 16 + e) * Hn + 0) * Wn + xw];

    const int cig = tid & 15;
    const int w0  = tid >> 4;

    unsigned long long qs[8];     // loop-carried snapshot (row-end poll)
    #pragma unroll
    for (int it = 0; it < 8; ++it) qs[it] = 0ull;

    int fastok = 1, failn = 0;    // adaptive fast-path disable (wave-uniform)

    for (int h = 0; h < Hn; ++h) {
        const int p_read  = (h > 0) ? (((h - 1) >> 1) & 1) : 0;
        const int p_store = (h >> 1) & 1;
        const unsigned short psign = (unsigned short)(p_read << 15);

        const int rd_par = (h & 1) ^ 1, wr_par = h & 1;
        const short* rd_llc = llc0 + rd_par * HBUF_SHORTS + b * Wn * HID;
        short*       wr_llc = llc0 + wr_par * HBUF_SHORTS + b * Wn * HID;
        const short* rd_l2  = l2b0 + rd_par * HBUF_SHORTS + b * Wn * HID;
        short*       wr_l2  = l2b0 + wr_par * HBUF_SHORTS + b * Wn * HID;

        // ---- consumer: validate snapshot, retry via L2, fall back to flags+LLC ----
        if (h > 0) {
            unsigned need = 0xFFu;
            bool fell = false;
            #pragma unroll
            for (int it = 0; it < 8; ++it) {
                if (qvalid(qs[it], psign)) {
                    const int w = w0 + (it >> 1) * 16;
                    *(unsigned long long*)&sH[(w + 1) * SHS + cig * 8 + (it & 1) * 4] = qs[it];
                    need &= ~(1u << it);
                }
            }
            int tries = 0;
            while (__any(need != 0)) {
                if (fastok && tries < RETRY) {
                    ++tries;
                    __builtin_amdgcn_s_sleep(1);
                    poll8(rd_l2 + (w0     ) * HID + cig * 8,
                          rd_l2 + (w0 + 16) * HID + cig * 8,
                          rd_l2 + (w0 + 32) * HID + cig * 8,
                          rd_l2 + (w0 + 48) * HID + cig * 8, qs);
                    #pragma unroll
                    for (int it = 0; it < 8; ++it) {
                        if ((need & (1u << it)) && qvalid(qs[it], psign)) {
                            const int w = w0 + (it >> 1) * 16;
                            *(unsigned long long*)&sH[(w + 1) * SHS + cig * 8 + (it & 1) * 4] = qs[it];
                            need &= ~(1u << it);
                        }
                    }
                } else {
                    fell = true;
                    const unsigned tgt = (unsigned)h;
                    for (;;) {
                        unsigned f = tgt;
                        if (lane < 32)
                            f = __hip_atomic_load(&flags[lane], __ATOMIC_RELAXED, __HIP_MEMORY_SCOPE_AGENT);
                        if (__all((int)(f >= tgt))) break;
                        __builtin_amdgcn_s_sleep(2);
                    }
                    #pragma unroll
                    for (int it = 0; it < 8; ++it) {
                        if (need & (1u << it)) {
                            const int w = w0 + (it >> 1) * 16;
                            const unsigned long long q = __hip_atomic_load(
                                (const unsigned long long*)(rd_llc + w * HID + cig * 8 + (it & 1) * 4),
                                __ATOMIC_RELAXED, __HIP_MEMORY_SCOPE_AGENT);
                            *(unsigned long long*)&sH[(w + 1) * SHS + cig * 8 + (it & 1) * 4] = q;
                        }
                    }
                    need = 0;
                }
            }
            if (h <= 4 && fell) ++failn;
            if (h == 5 && failn >= 3) fastok = 0;   // placement adverse: stop paying retries
        } else {
            // h==0: h_prev = 0 -> encoded +2.0, phase 0
            const unsigned long long fillv = 0x4000400040004000ULL;
            #pragma unroll
            for (int it = 0; it < 8; ++it) {
                const int w = w0 + (it >> 1) * 16;
                *(unsigned long long*)&sH[(w + 1) * SHS + cig * 8 + (it & 1) * 4] = fillv;
            }
        }

        // ---- sH guard rows: encoded zero = sgn*2.0 for the phase being read ----
        {
            const unsigned long long g = p_read ? 0xC000C000C000C000ULL : 0x4000400040004000ULL;
            if (tid < 16) {
                *(unsigned long long*)&sH[tid * 8]     = g;
                *(unsigned long long*)&sH[tid * 8 + 4] = g;
            } else if (tid < 32) {
                const int t = tid - 16;
                *(unsigned long long*)&sH[65 * SHS + t * 8]     = g;
                *(unsigned long long*)&sH[65 * SHS + t * 8 + 4] = g;
            }
        }

        // ---- build x panel (fp16) from xr prefetched last row ----
        {
            h8_t v0, v1;
            #pragma unroll
            for (int e = 0; e < 8; ++e) { v0[e] = (_Float16)xr[e]; v1[e] = (_Float16)xr[e + 8]; }
            *(h8_t*)&sX2[(xw + 1) * SXS2 + xc2 * 16]     = v0;
            *(h8_t*)&sX2[(xw + 1) * SXS2 + xc2 * 16 + 8] = v1;
        }

        BAR_LGKM();   // S1: panels ready

        // ---- GEMM, K=512: x-part (unencoded) and h-part (encoded) in separate accs ----
        f4_t ac0 = {0,0,0,0}, ac1 = {0,0,0,0}, ac2 = {0,0,0,0}, ac3 = {0,0,0,0};
        #pragma unroll
        for (int kt = 0; kt < 4; ++kt) {
            const short* src = &sX2[(wp + (kt >> 1)) * SXS2 + (kt & 1) * 32 + quad * 8];
            h8_t bf = *(const h8_t*)src;
            ac0 = __builtin_amdgcn_mfma_f32_16x16x32_f16(a_frag[0][kt], bf, ac0, 0, 0, 0);
            ac1 = __builtin_amdgcn_mfma_f32_16x16x32_f16(a_frag[1][kt], bf, ac1, 0, 0, 0);
            ac2 = __builtin_amdgcn_mfma_f32_16x16x32_f16(a_frag[2][kt], bf, ac2, 0, 0, 0);
            ac3 = __builtin_amdgcn_mfma_f32_16x16x32_f16(a_frag[3][kt], bf, ac3, 0, 0, 0);
        }
        f4_t ah0 = {0,0,0,0}, ah1 = {0,0,0,0}, ah2 = {0,0,0,0}, ah3 = {0,0,0,0};
        #pragma unroll
        for (int kt = 4; kt < 16; ++kt) {
            const short* src = &sH[(wp + ((kt - 4) >> 2)) * SHS + ((kt - 4) & 3) * 32 + quad * 8];
            h8_t bf = *(const h8_t*)src;
            ah0 = __builtin_amdgcn_mfma_f32_16x16x32_f16(a_frag[0][kt], bf, ah0, 0, 0, 0);
            ah1 = __builtin_amdgcn_mfma_f32_16x16x32_f16(a_frag[1][kt], bf, ah1, 0, 0, 0);
            ah2 = __builtin_amdgcn_mfma_f32_16x16x32_f16(a_frag[2][kt], bf, ah2, 0, 0, 0);
            ah3 = __builtin_amdgcn_mfma_f32_16x16x32_f16(a_frag[3][kt], bf, ah3, 0, 0, 0);
        }

        // ---- phase C: z = z_x + sgn*acc_h + (bias - 2*S3); lane-local ----
        float hv[4];
        const float sg = p_read ? -1.f : 1.f;
        #pragma unroll
        for (int r = 0; r < 4; ++r) {
            float ig = sigm (ac0[r] + sg * ah0[r] + bias2[0][r]);
            float fg = sigm (ac1[r] + sg * ah1[r] + bias2[1][r]);
            float og = sigm (ac2[r] + sg * ah2[r] + bias2[2][r]);
            float gg = tanhf_(ac3[r] + sg * ah3[r] + bias2[3][r]);
            float c  = fg * creg[r] + ig * gg;
            creg[r]  = c;
            hv[r]    = og * tanhf_(c);
        }

        if (h + 1 < Hn) {
            // next-row x prefetch first: its latency hides under the store/drain
            #pragma unroll
            for (int e = 0; e < 16; ++e)
                xr[e] = x[((b * CIN + xc2 * 16 + e) * Hn + (h + 1)) * Wn + xw];

            // encoded h: sgn*(h+2), 4x fp16 packed -> L2 (plain) + LLC (agent)
            unsigned long long pk = 0;
            #pragma unroll
            for (int r = 0; r < 4; ++r) {
                float ef = hv[r] + 2.f;
                if (p_store) ef = -ef;
                union { _Float16 f; unsigned short s; } u;
                u.f = (_Float16)ef;
                pk |= ((unsigned long long)u.s) << (16 * r);
            }
            const int doff = wp * HID + jc * 16 + quad * 4;
            *(unsigned long long*)(wr_l2 + doff) = pk;                       // fast-path copy
            __hip_atomic_store((unsigned long long*)(wr_llc + doff), pk,
                               __ATOMIC_RELAXED, __HIP_MEMORY_SCOPE_AGENT);  // fallback copy

            // out-stores (off the consumer path; drained by the snapshot below)
            #pragma unroll
            for (int r = 0; r < 4; ++r)
                out[((b * HID + jc * 16 + quad * 4 + r) * Hn + h) * Wn + wp] = hv[r];

            // row-end snapshot of NEXT row's read buffer (= wr_l2). Its trailing vmcnt(0)
            // is also the drain that orders the flag store after all h/out stores.
            poll8(wr_l2 + (w0     ) * HID + cig * 8,
                  wr_l2 + (w0 + 16) * HID + cig * 8,
                  wr_l2 + (w0 + 32) * HID + cig * 8,
                  wr_l2 + (w0 + 48) * HID + cig * 8, qs);
            if (lane == 0)
                __hip_atomic_store(&flags[jc * 4 + wv], (unsigned)(h + 1),
                                   __ATOMIC_RELAXED, __HIP_MEMORY_SCOPE_AGENT);
        } else {
            #pragma unroll
            for (int r = 0; r < 4; ++r)
                out[((b * HID + jc * 16 + quad * 4 + r) * Hn + h) * Wn + wp] = hv[r];
        }

        BAR_LGKM();   // S2: all LDS reads done; panels reusable next row (no vm drain)
    }
}

extern "C" void kernel_launch(void* const* d_in, const int* in_sizes, int n_in,
                              void* d_out, int out_size, void* d_ws, size_t ws_size,
                              hipStream_t stream) {
    const float* x    = (const float*)d_in[0];
    const float* w_is = (const float*)d_in[1];
    const float* b_is = (const float*)d_in[2];
    const float* w_ss = (const float*)d_in[3];
    const float* b_ss = (const float*)d_in[4];
    float* out = (float*)d_out;
    unsigned char* ws = (unsigned char*)d_ws;

    // zero both regions' both buffers (0x0000 fails both validity windows) + flags
    hipMemsetAsync(ws, 0, 4 * HBUF_BYTES + B_ * FLG_STRIDE, stream);

    // 128 blocks (8 j-chunks x 16 batches), ~27KB LDS, 1 block/CU -> all co-resident.
    rowlstm_kernel<<<dim3(NBLK), dim3(256), 0, stream>>>(x, w_is, b_is, w_ss, b_ss, out, ws);
}

// Round 6
// 415.203 us; speedup vs baseline: 1.3818x; 1.3818x over previous
//
#include <hip/hip_runtime.h>
#include <hip/hip_bf16.h>

#define B_    16
#define CIN   64
#define Hn    64
#define Wn    64
#define HID   128
#define NJC   8     // j-chunks per batch (16 channels each)
#define NBLK  (B_ * NJC)
#define SXROW 160   // sX2 row pitch in BYTES (40 dwords: 4-way worst on reads, swizzled)

typedef __attribute__((ext_vector_type(8))) short bfrag_t;   // 8 bf16 (4 VGPRs)
typedef __attribute__((ext_vector_type(4))) float f4_t;

// d_ws layout:
//   [0, 256KB)        : h_buf[0]  bf16 [16][64][128]   (b, w, ci)
//   [256KB, 512KB)    : h_buf[1]  (step h writes buf[h&1], reads buf[h&1^1])
//   [512KB, +4KB)     : per-b flag line (256B): flags[jc] = rows completed by block (b,jc)
#define HBUF_SHORTS (B_ * Wn * HID)
#define HBUF_BYTES  (HBUF_SHORTS * 2)
#define FLG_STRIDE  256

static __device__ __forceinline__ short f2bf(float f) {
    union { __hip_bfloat16 h; short s; } u;
    u.h = __float2bfloat16(f);
    return u.s;
}
static __device__ __forceinline__ float sigm(float z)  { return 1.f / (1.f + __expf(-z)); }
static __device__ __forceinline__ float tanhf_(float z){ return 2.f / (1.f + __expf(-2.f * z)) - 1.f; }

// lgkm-only barrier: never drains vmcnt (out-stores/prefetches stay in flight).
#define BAR_LGKM() do { \
    asm volatile("s_waitcnt lgkmcnt(0)" ::: "memory"); \
    __builtin_amdgcn_s_barrier(); \
    __builtin_amdgcn_sched_barrier(0); \
} while (0)

extern "C" __global__ __launch_bounds__(256, 1)
void rowlstm_kernel(const float* __restrict__ x,
                    const float* __restrict__ w_is,
                    const float* __restrict__ b_is,
                    const float* __restrict__ w_ss,
                    const float* __restrict__ b_ss,
                    float* __restrict__ out,
                    unsigned char* __restrict__ ws)
{
    const int tid  = threadIdx.x;
    const int bid  = blockIdx.x;
    const int b    = bid & 15;        // batch; same-b blocks share bid%8 (L2 heuristic only)
    const int jc   = bid >> 4;        // j-chunk: channels [jc*16, jc*16+16)
    const int lane = tid & 63;
    const int wv   = tid >> 6;        // wave id = N-tile (16 w's)
    const int l15  = lane & 15;
    const int quad = lane >> 4;

    short*    hbuf0 = (short*)ws;
    unsigned* flags = (unsigned*)(ws + 2 * HBUF_BYTES + b * FLG_STRIDE);  // 8 words, one line

    // LDS: only the x panel now (h goes direct-to-fragment from LLC). ~10.4 KB.
    // Row w' = x[.][w'-1]; row 0 = zero guard. 16B units XOR-swizzled by row.
    __shared__ alignas(16) unsigned char sX2[65 * SXROW];

    // ---- A (weight) fragments, gate-major: M-row = mt*16 + l15 -> gate mt, ch l15.
    // K layout (512): [0,64) x kw0 | [64,128) x kw1 | [128,256) h kw0 | [256,384) h kw1 | [384,512) h kw2
    bfrag_t a_frag[4][16];
    #pragma unroll
    for (int mt = 0; mt < 4; ++mt) {
        const int co = mt * HID + jc * 16 + l15;
        #pragma unroll
        for (int kt = 0; kt < 16; ++kt) {
            const int kk0 = kt * 32 + quad * 8;
            const float* p;
            if      (kt < 2)  p = &w_is[(co * CIN + kk0)         * 3 + 0];
            else if (kt < 4)  p = &w_is[(co * CIN + (kk0 - 64))  * 3 + 1];
            else if (kt < 8)  p = &w_ss[(co * HID + (kk0 - 128)) * 3 + 0];
            else if (kt < 12) p = &w_ss[(co * HID + (kk0 - 256)) * 3 + 1];
            else              p = &w_ss[(co * HID + (kk0 - 384)) * 3 + 2];
            bfrag_t v;
            #pragma unroll
            for (int j = 0; j < 8; ++j) v[j] = f2bf(p[j * 3]);
            a_frag[mt][kt] = v;
        }
    }

    // per-thread biases: 4 gates x 4 channels (this thread's channels = quad*4 + r)
    float bias[4][4];
    #pragma unroll
    for (int g = 0; g < 4; ++g) {
        #pragma unroll
        for (int r = 0; r < 4; ++r) {
            const int co = g * HID + jc * 16 + quad * 4 + r;
            bias[g][r] = b_is[co] + b_ss[co];
        }
    }

    // zero guard row 0 of sX2 (row 0 swizzle is identity)
    {
        bfrag_t z8 = {0,0,0,0,0,0,0,0};
        if (tid < 8) *(bfrag_t*)&sX2[tid * 16] = z8;
    }

    float creg[4] = {0.f, 0.f, 0.f, 0.f};
    const int wp  = wv * 16 + l15;    // this thread's w (GEMM col and phase C)

    // x staging: thread (xw, xc2) holds x[ci = xc2*16 .. +15][xw]
    const int xw  = tid & 63;
    const int xc2 = tid >> 6;
    float xr[16];
    #pragma unroll
    for (int e = 0; e < 16; ++e)
        xr[e] = x[((b * CIN + xc2 * 16 + e) * Hn + 0) * Wn + xw];

    // build sX2 for row 0, prefetch row 1
    {
        const int row = xw + 1, sw = (row & 7) << 4;
        bfrag_t v0, v1;
        #pragma unroll
        for (int e = 0; e < 8; ++e) { v0[e] = f2bf(xr[e]); v1[e] = f2bf(xr[e + 8]); }
        *(bfrag_t*)&sX2[row * SXROW + ((xc2 * 32)      ^ sw)] = v0;
        *(bfrag_t*)&sX2[row * SXROW + ((xc2 * 32 + 16) ^ sw)] = v1;
        #pragma unroll
        for (int e = 0; e < 16; ++e)
            xr[e] = x[((b * CIN + xc2 * 16 + e) * Hn + 1) * Wn + xw];
    }
    __syncthreads();

    for (int h = 0; h < Hn; ++h) {
        const short* rd_hb = hbuf0 + ((h & 1) ^ 1) * HBUF_SHORTS + b * Wn * HID;
        short*       wr_hb = hbuf0 + (h & 1) * HBUF_SHORTS + b * Wn * HID;

        // ---- all-thread spin (wave-coalesced: lane l checks flag[l&7]) ----
        union { bfrag_t f; unsigned long long q[2]; } bh[12];
        if (h > 0) {
            const unsigned tgt = (unsigned)h;
            for (;;) {
                unsigned f = __hip_atomic_load(&flags[lane & 7],
                                               __ATOMIC_RELAXED, __HIP_MEMORY_SCOPE_AGENT);
                if (__all((int)(f >= tgt))) break;
                __builtin_amdgcn_s_sleep(1);
            }
            asm volatile("" ::: "memory");   // keep the frag loads below the spin

            // ---- direct-to-fragment h loads: 12 x 16B, latency hidden by x-GEMM ----
            #pragma unroll
            for (int t = 0; t < 3; ++t) {
                const int  w_read = wp + t - 1;
                const bool valid  = ((unsigned)w_read < (unsigned)Wn);
                const short* base = rd_hb + (valid ? w_read : 0) * HID + quad * 8;
                #pragma unroll
                for (int cb = 0; cb < 4; ++cb) {
                    const unsigned long long* s = (const unsigned long long*)(base + cb * 32);
                    bh[t * 4 + cb].q[0] = __hip_atomic_load(s,     __ATOMIC_RELAXED, __HIP_MEMORY_SCOPE_AGENT);
                    bh[t * 4 + cb].q[1] = __hip_atomic_load(s + 1, __ATOMIC_RELAXED, __HIP_MEMORY_SCOPE_AGENT);
                }
            }
        }

        // ---- x-GEMM (kt 0..3) from sX2 while the h loads fly ----
        f4_t acc0 = {0.f,0.f,0.f,0.f}, acc1 = {0.f,0.f,0.f,0.f};
        f4_t acc2 = {0.f,0.f,0.f,0.f}, acc3 = {0.f,0.f,0.f,0.f};
        #pragma unroll
        for (int kt = 0; kt < 4; ++kt) {
            const int row  = wp + (kt >> 1);
            const int boff = ((kt & 1) * 64 + quad * 16) ^ ((row & 7) << 4);
            bfrag_t bf = *(const bfrag_t*)&sX2[row * SXROW + boff];
            acc0 = __builtin_amdgcn_mfma_f32_16x16x32_bf16(a_frag[0][kt], bf, acc0, 0, 0, 0);
            acc1 = __builtin_amdgcn_mfma_f32_16x16x32_bf16(a_frag[1][kt], bf, acc1, 0, 0, 0);
            acc2 = __builtin_amdgcn_mfma_f32_16x16x32_bf16(a_frag[2][kt], bf, acc2, 0, 0, 0);
            acc3 = __builtin_amdgcn_mfma_f32_16x16x32_bf16(a_frag[3][kt], bf, acc3, 0, 0, 0);
        }

        // ---- h-GEMM (kt 4..15) straight from the loaded fragments ----
        if (h > 0) {
            asm volatile("s_waitcnt vmcnt(0)" ::: "memory");   // frags ready (also retires old stores)
            __builtin_amdgcn_sched_barrier(0);
            // boundary taps -> zero (only lanes wp==0 / wp==63)
            if (wp == 0) {
                #pragma unroll
                for (int cb = 0; cb < 4; ++cb) { bh[cb].q[0] = 0ull; bh[cb].q[1] = 0ull; }
            }
            if (wp == Wn - 1) {
                #pragma unroll
                for (int cb = 0; cb < 4; ++cb) { bh[8 + cb].q[0] = 0ull; bh[8 + cb].q[1] = 0ull; }
            }
            #pragma unroll
            for (int kt = 4; kt < 16; ++kt) {
                bfrag_t bf = bh[kt - 4].f;
                acc0 = __builtin_amdgcn_mfma_f32_16x16x32_bf16(a_frag[0][kt], bf, acc0, 0, 0, 0);
                acc1 = __builtin_amdgcn_mfma_f32_16x16x32_bf16(a_frag[1][kt], bf, acc1, 0, 0, 0);
                acc2 = __builtin_amdgcn_mfma_f32_16x16x32_bf16(a_frag[2][kt], bf, acc2, 0, 0, 0);
                acc3 = __builtin_amdgcn_mfma_f32_16x16x32_bf16(a_frag[3][kt], bf, acc3, 0, 0, 0);
            }
        }

        // ---- phase C: fully lane-local ----
        float hv[4];
        #pragma unroll
        for (int r = 0; r < 4; ++r) {
            float ig = sigm (acc0[r] + bias[0][r]);
            float fg = sigm (acc1[r] + bias[1][r]);
            float og = sigm (acc2[r] + bias[2][r]);
            float gg = tanhf_(acc3[r] + bias[3][r]);
            float c  = fg * creg[r] + ig * gg;
            creg[r]  = c;
            hv[r]    = og * tanhf_(c);
        }

        // ---- h-store: the ONLY outstanding VM op at the next drain ----
        if (h + 1 < Hn) {
            unsigned p0 = (unsigned)(unsigned short)f2bf(hv[0]) |
                          ((unsigned)(unsigned short)f2bf(hv[1]) << 16);
            unsigned p1 = (unsigned)(unsigned short)f2bf(hv[2]) |
                          ((unsigned)(unsigned short)f2bf(hv[3]) << 16);
            unsigned long long pk = (unsigned long long)p0 | ((unsigned long long)p1 << 32);
            __hip_atomic_store((unsigned long long*)(wr_hb + wp * HID + jc * 16 + quad * 4),
                               pk, __ATOMIC_RELAXED, __HIP_MEMORY_SCOPE_AGENT);
        }
        __syncthreads();   // S2: drains h-stores (all older VM retired at the mid-row vmcnt(0))

        if (h + 1 < Hn && tid == 0)
            __hip_atomic_store(&flags[jc], (unsigned)(h + 1),
                               __ATOMIC_RELAXED, __HIP_MEMORY_SCOPE_AGENT);

        // ---- off-chain tail: build sX2(h+1), out-stores, prefetch x(h+2) ----
        if (h + 1 < Hn) {
            const int row = xw + 1, sw = (row & 7) << 4;
            bfrag_t v0, v1;
            #pragma unroll
            for (int e = 0; e < 8; ++e) { v0[e] = f2bf(xr[e]); v1[e] = f2bf(xr[e + 8]); }
            *(bfrag_t*)&sX2[row * SXROW + ((xc2 * 32)      ^ sw)] = v0;
            *(bfrag_t*)&sX2[row * SXROW + ((xc2 * 32 + 16) ^ sw)] = v1;
        }

        #pragma unroll
        for (int r = 0; r < 4; ++r)
            out[((b * HID + jc * 16 + quad * 4 + r) * Hn + h) * Wn + wp] = hv[r];

        if (h + 2 < Hn) {
            #pragma unroll
            for (int e = 0; e < 16; ++e)
                xr[e] = x[((b * CIN + xc2 * 16 + e) * Hn + (h + 2)) * Wn + xw];
        }

        if (h + 1 < Hn)
            BAR_LGKM();   // S3: sX2(h+1) visible to all waves; VM ops stay in flight
    }
}

extern "C" void kernel_launch(void* const* d_in, const int* in_sizes, int n_in,
                              void* d_out, int out_size, void* d_ws, size_t ws_size,
                              hipStream_t stream) {
    const float* x    = (const float*)d_in[0];
    const float* w_is = (const float*)d_in[1];
    const float* b_is = (const float*)d_in[2];
    const float* w_ss = (const float*)d_in[3];
    const float* b_ss = (const float*)d_in[4];
    float* out = (float*)d_out;
    unsigned char* ws = (unsigned char*)d_ws;

    hipMemsetAsync(ws + 2 * HBUF_BYTES, 0, B_ * FLG_STRIDE, stream);

    // 128 blocks (8 j-chunks x 16 batches), ~10KB LDS, 1 block/CU -> all co-resident.
    rowlstm_kernel<<<dim3(NBLK), dim3(256), 0, stream>>>(x, w_is, b_is, w_ss, b_ss, out, ws);
}

// Round 7
// 314.216 us; speedup vs baseline: 1.8259x; 1.3214x over previous
//
#include <hip/hip_runtime.h>
#include <hip/hip_bf16.h>

#define B_    16
#define CIN   64
#define Hn    64
#define Wn    64
#define HID   128
#define SXS2  72    // sX2 row stride in shorts (144B, 16B-aligned)
#define SHS   136   // sH  row stride in shorts (272B, 16B-aligned)
#define NJC   8     // j-chunks per batch (16 channels each)
#define NBLK  (B_ * NJC)

typedef __attribute__((ext_vector_type(8))) short bfrag_t;   // 8 bf16 (4 VGPRs)
typedef __attribute__((ext_vector_type(4))) float f4_t;

// d_ws layout:
//   [0, 256KB)        : h_buf[0]  bf16 [16][64][128]   (b, w, ci)
//   [256KB, 512KB)    : h_buf[1]  (step h writes buf[h&1], reads buf[h&1^1])
//   [512KB, +4KB)     : per-b flag line (256B): flags[jc*4+wv] = rows completed by that wave
#define HBUF_SHORTS (B_ * Wn * HID)
#define HBUF_BYTES  (HBUF_SHORTS * 2)
#define FLG_STRIDE  256

static __device__ __forceinline__ short f2bf(float f) {
    union { __hip_bfloat16 h; short s; } u;
    u.h = __float2bfloat16(f);
    return u.s;
}
static __device__ __forceinline__ float sigm(float z)  { return 1.f / (1.f + __expf(-z)); }
static __device__ __forceinline__ float tanhf_(float z){ return 2.f / (1.f + __expf(-2.f * z)) - 1.f; }

// lgkm-only barrier: never drains vmcnt (out-stores/prefetches stay in flight).
#define BAR_LGKM() do { \
    asm volatile("s_waitcnt lgkmcnt(0)" ::: "memory"); \
    __builtin_amdgcn_s_barrier(); \
    __builtin_amdgcn_sched_barrier(0); \
} while (0)

extern "C" __global__ __launch_bounds__(256, 1)
void rowlstm_kernel(const float* __restrict__ x,
                    const float* __restrict__ w_is,
                    const float* __restrict__ b_is,
                    const float* __restrict__ w_ss,
                    const float* __restrict__ b_ss,
                    float* __restrict__ out,
                    unsigned char* __restrict__ ws)
{
    const int tid  = threadIdx.x;
    const int bid  = blockIdx.x;
    const int b    = bid & 15;        // batch; same-b blocks share bid%8 (L2 heuristic only)
    const int jc   = bid >> 4;        // j-chunk: channels [jc*16, jc*16+16)
    const int lane = tid & 63;
    const int wv   = tid >> 6;        // wave id = N-tile (16 w's)
    const int l15  = lane & 15;
    const int quad = lane >> 4;

    short*    hbuf0 = (short*)ws;
    unsigned* flags = (unsigned*)(ws + 2 * HBUF_BYTES + b * FLG_STRIDE);  // 32 words, one line

    // LDS ~27 KB. Shifted-read panels: tap t of column w' reads row w'+t. (R1 layout, unchanged.)
    __shared__ alignas(16) short sH[66 * SHS];    // h panel, rows 0..65 (0,65 = zero guards)
    __shared__ alignas(16) short sX2[65 * SXS2];  // x panel, rows 0..64 (0 = zero guard)

    // ---- A (weight) fragments, gate-major: M-row = mt*16 + l15 -> gate mt, ch l15.
    // K layout (512): [0,64) x kw0 | [64,128) x kw1 | [128,256) h kw0 | [256,384) h kw1 | [384,512) h kw2
    bfrag_t a_frag[4][16];
    #pragma unroll
    for (int mt = 0; mt < 4; ++mt) {
        const int co = mt * HID + jc * 16 + l15;
        #pragma unroll
        for (int kt = 0; kt < 16; ++kt) {
            const int kk0 = kt * 32 + quad * 8;   // region constant per (kt,quad)
            const float* p;
            if      (kt < 2)  p = &w_is[(co * CIN + kk0)         * 3 + 0];
            else if (kt < 4)  p = &w_is[(co * CIN + (kk0 - 64))  * 3 + 1];
            else if (kt < 8)  p = &w_ss[(co * HID + (kk0 - 128)) * 3 + 0];
            else if (kt < 12) p = &w_ss[(co * HID + (kk0 - 256)) * 3 + 1];
            else              p = &w_ss[(co * HID + (kk0 - 384)) * 3 + 2];
            bfrag_t v;
            #pragma unroll
            for (int j = 0; j < 8; ++j) v[j] = f2bf(p[j * 3]);
            a_frag[mt][kt] = v;
        }
    }

    // per-thread biases: 4 gates x 4 channels (this thread's channels = quad*4 + r)
    float bias[4][4];
    #pragma unroll
    for (int g = 0; g < 4; ++g) {
        #pragma unroll
        for (int r = 0; r < 4; ++r) {
            const int co = g * HID + jc * 16 + quad * 4 + r;
            bias[g][r] = b_is[co] + b_ss[co];
        }
    }

    // zero guard rows (never touched again)
    {
        bfrag_t z8 = {0,0,0,0,0,0,0,0};
        if (tid < 8)  *(bfrag_t*)&sX2[tid * 8] = z8;                 // sX2 row 0 (64 ci)
        if (tid < 16) {
            *(bfrag_t*)&sH[tid * 8] = z8;                            // sH row 0
            *(bfrag_t*)&sH[65 * SHS + tid * 8] = z8;                 // sH row 65
        }
    }

    float creg[4] = {0.f, 0.f, 0.f, 0.f};
    const int wp  = wv * 16 + l15;    // this thread's w (GEMM col and phase C)

    // x staging: thread (xw, xc2) holds x[ci = xc2*16 .. +15][xw]
    const int xw  = tid & 63;
    const int xc2 = tid >> 6;
    float xr[16];
    #pragma unroll
    for (int e = 0; e < 16; ++e)
        xr[e] = x[((b * CIN + xc2 * 16 + e) * Hn + 0) * Wn + xw];

    // prologue: build x panel for row 0, prefetch row 1
    {
        bfrag_t v0, v1;
        #pragma unroll
        for (int e = 0; e < 8; ++e) { v0[e] = f2bf(xr[e]); v1[e] = f2bf(xr[e + 8]); }
        *(bfrag_t*)&sX2[(xw + 1) * SXS2 + xc2 * 16]     = v0;
        *(bfrag_t*)&sX2[(xw + 1) * SXS2 + xc2 * 16 + 8] = v1;
        #pragma unroll
        for (int e = 0; e < 16; ++e)
            xr[e] = x[((b * CIN + xc2 * 16 + e) * Hn + 1) * Wn + xw];
    }

    const int cig = tid & 15;     // 8-ch group within panel staging
    const int w0  = tid >> 4;     // base w for panel staging

    __syncthreads();

    for (int h = 0; h < Hn; ++h) {
        const short* rd_hb = hbuf0 + ((h & 1) ^ 1) * HBUF_SHORTS + b * Wn * HID;
        short*       wr_hb = hbuf0 + (h & 1) * HBUF_SHORTS + b * Wn * HID;

        // ---- HEAD: all-thread spin on the 32 per-wave flags (one coalesced line) ----
        union { bfrag_t f; unsigned long long q[2]; } hu0, hu1, hu2, hu3;
        if (h > 0) {
            const unsigned tgt = (unsigned)h;
            for (;;) {
                unsigned f = __hip_atomic_load(&flags[lane & 31],
                                               __ATOMIC_RELAXED, __HIP_MEMORY_SCOPE_AGENT);
                if (__all((int)(f >= tgt))) break;
                __builtin_amdgcn_s_sleep(1);
            }
            asm volatile("" ::: "memory");   // keep h-loads below the spin

            // coalesced h loads (identical addressing to R1's 245 µs kernel)
            const unsigned long long* s0 = (const unsigned long long*)(rd_hb + (w0     ) * HID + cig * 8);
            const unsigned long long* s1 = (const unsigned long long*)(rd_hb + (w0 + 16) * HID + cig * 8);
            const unsigned long long* s2 = (const unsigned long long*)(rd_hb + (w0 + 32) * HID + cig * 8);
            const unsigned long long* s3 = (const unsigned long long*)(rd_hb + (w0 + 48) * HID + cig * 8);
            hu0.q[0] = __hip_atomic_load(s0,     __ATOMIC_RELAXED, __HIP_MEMORY_SCOPE_AGENT);
            hu0.q[1] = __hip_atomic_load(s0 + 1, __ATOMIC_RELAXED, __HIP_MEMORY_SCOPE_AGENT);
            hu1.q[0] = __hip_atomic_load(s1,     __ATOMIC_RELAXED, __HIP_MEMORY_SCOPE_AGENT);
            hu1.q[1] = __hip_atomic_load(s1 + 1, __ATOMIC_RELAXED, __HIP_MEMORY_SCOPE_AGENT);
            hu2.q[0] = __hip_atomic_load(s2,     __ATOMIC_RELAXED, __HIP_MEMORY_SCOPE_AGENT);
            hu2.q[1] = __hip_atomic_load(s2 + 1, __ATOMIC_RELAXED, __HIP_MEMORY_SCOPE_AGENT);
            hu3.q[0] = __hip_atomic_load(s3,     __ATOMIC_RELAXED, __HIP_MEMORY_SCOPE_AGENT);
            hu3.q[1] = __hip_atomic_load(s3 + 1, __ATOMIC_RELAXED, __HIP_MEMORY_SCOPE_AGENT);
        } else {
            hu0.q[0] = hu0.q[1] = 0ull; hu1.q[0] = hu1.q[1] = 0ull;
            hu2.q[0] = hu2.q[1] = 0ull; hu3.q[0] = hu3.q[1] = 0ull;
        }

        // ---- x-GEMM (kt 0..3) from the panel built last tail; h-load latency hides here ----
        f4_t acc0 = {0.f,0.f,0.f,0.f}, acc1 = {0.f,0.f,0.f,0.f};
        f4_t acc2 = {0.f,0.f,0.f,0.f}, acc3 = {0.f,0.f,0.f,0.f};
        #pragma unroll
        for (int kt = 0; kt < 4; ++kt) {
            const short* src = &sX2[(wp + (kt >> 1)) * SXS2 + (kt & 1) * 32 + quad * 8];
            bfrag_t bf = *(const bfrag_t*)src;
            acc0 = __builtin_amdgcn_mfma_f32_16x16x32_bf16(a_frag[0][kt], bf, acc0, 0, 0, 0);
            acc1 = __builtin_amdgcn_mfma_f32_16x16x32_bf16(a_frag[1][kt], bf, acc1, 0, 0, 0);
            acc2 = __builtin_amdgcn_mfma_f32_16x16x32_bf16(a_frag[2][kt], bf, acc2, 0, 0, 0);
            acc3 = __builtin_amdgcn_mfma_f32_16x16x32_bf16(a_frag[3][kt], bf, acc3, 0, 0, 0);
        }

        // ---- h panel writes (compiler inserts precise vmcnt waits for hu*) ----
        *(bfrag_t*)&sH[(w0 +  1) * SHS + cig * 8] = hu0.f;
        *(bfrag_t*)&sH[(w0 + 17) * SHS + cig * 8] = hu1.f;
        *(bfrag_t*)&sH[(w0 + 33) * SHS + cig * 8] = hu2.f;
        *(bfrag_t*)&sH[(w0 + 49) * SHS + cig * 8] = hu3.f;
        BAR_LGKM();   // S1: sH ready (only head barrier)

        // ---- h-GEMM (kt 4..15) ----
        #pragma unroll
        for (int kt = 4; kt < 16; ++kt) {
            const short* src = &sH[(wp + ((kt - 4) >> 2)) * SHS + ((kt - 4) & 3) * 32 + quad * 8];
            bfrag_t bf = *(const bfrag_t*)src;
            acc0 = __builtin_amdgcn_mfma_f32_16x16x32_bf16(a_frag[0][kt], bf, acc0, 0, 0, 0);
            acc1 = __builtin_amdgcn_mfma_f32_16x16x32_bf16(a_frag[1][kt], bf, acc1, 0, 0, 0);
            acc2 = __builtin_amdgcn_mfma_f32_16x16x32_bf16(a_frag[2][kt], bf, acc2, 0, 0, 0);
            acc3 = __builtin_amdgcn_mfma_f32_16x16x32_bf16(a_frag[3][kt], bf, acc3, 0, 0, 0);
        }

        // ---- phase C: fully lane-local ----
        float hv[4];
        #pragma unroll
        for (int r = 0; r < 4; ++r) {
            float ig = sigm (acc0[r] + bias[0][r]);
            float fg = sigm (acc1[r] + bias[1][r]);
            float og = sigm (acc2[r] + bias[2][r]);
            float gg = tanhf_(acc3[r] + bias[3][r]);
            float c  = fg * creg[r] + ig * gg;
            creg[r]  = c;
            hv[r]    = og * tanhf_(c);
        }

        // ---- TAIL chain: h-store -> per-wave vmcnt(0) -> per-wave flag. Nothing else drains. ----
        if (h + 1 < Hn) {
            unsigned p0 = (unsigned)(unsigned short)f2bf(hv[0]) |
                          ((unsigned)(unsigned short)f2bf(hv[1]) << 16);
            unsigned p1 = (unsigned)(unsigned short)f2bf(hv[2]) |
                          ((unsigned)(unsigned short)f2bf(hv[3]) << 16);
            unsigned long long pk = (unsigned long long)p0 | ((unsigned long long)p1 << 32);
            __hip_atomic_store((unsigned long long*)(wr_hb + wp * HID + jc * 16 + quad * 4),
                               pk, __ATOMIC_RELAXED, __HIP_MEMORY_SCOPE_AGENT);
            asm volatile("s_waitcnt vmcnt(0)" ::: "memory");   // only the h-store is outstanding
            if (lane == 0)
                __hip_atomic_store(&flags[jc * 4 + wv], (unsigned)(h + 1),
                                   __ATOMIC_RELAXED, __HIP_MEMORY_SCOPE_AGENT);
        }

        __syncthreads();   // S2: LDS panels reusable (vm side already drained per-wave)

        // ---- off-chain tail: build sX2(h+1), out-stores, prefetch x(h+2) ----
        if (h + 1 < Hn) {
            bfrag_t v0, v1;
            #pragma unroll
            for (int e = 0; e < 8; ++e) { v0[e] = f2bf(xr[e]); v1[e] = f2bf(xr[e + 8]); }
            *(bfrag_t*)&sX2[(xw + 1) * SXS2 + xc2 * 16]     = v0;
            *(bfrag_t*)&sX2[(xw + 1) * SXS2 + xc2 * 16 + 8] = v1;
        }

        #pragma unroll
        for (int r = 0; r < 4; ++r)
            out[((b * HID + jc * 16 + quad * 4 + r) * Hn + h) * Wn + wp] = hv[r];

        if (h + 2 < Hn) {
            #pragma unroll
            for (int e = 0; e < 16; ++e)
                xr[e] = x[((b * CIN + xc2 * 16 + e) * Hn + (h + 2)) * Wn + xw];
        }

        if (h + 1 < Hn)
            BAR_LGKM();   // S3: sX2(h+1) visible; VM ops stay in flight
    }
}

extern "C" void kernel_launch(void* const* d_in, const int* in_sizes, int n_in,
                              void* d_out, int out_size, void* d_ws, size_t ws_size,
                              hipStream_t stream) {
    const float* x    = (const float*)d_in[0];
    const float* w_is = (const float*)d_in[1];
    const float* b_is = (const float*)d_in[2];
    const float* w_ss = (const float*)d_in[3];
    const float* b_ss = (const float*)d_in[4];
    float* out = (float*)d_out;
    unsigned char* ws = (unsigned char*)d_ws;

    hipMemsetAsync(ws + 2 * HBUF_BYTES, 0, B_ * FLG_STRIDE, stream);

    // 128 blocks (8 j-chunks x 16 batches), ~27KB LDS, 1 block/CU -> all co-resident.
    rowlstm_kernel<<<dim3(NBLK), dim3(256), 0, stream>>>(x, w_is, b_is, w_ss, b_ss, out, ws);
}